// Round 15
// baseline (168.367 us; speedup 1.0000x reference)
//
#include <hip/hip_runtime.h>

#define KTAGS 11
#define SS    13
#define TT    1024
#define BB    4096
#define GPW   4      // (fallback) chains per 64-thread block
#define UNR   8
#define HALF  512
#define LN2   0.6931471805599453f

typedef float        v4f __attribute__((ext_vector_type(4)));
typedef unsigned int v2u __attribute__((ext_vector_type(2)));

// ws layout (floats) — same as r10/r13 (known to fit)
#define WS_VA   0            // v = M^T a_511   [11][BB]
#define WS_UB   (11*BB)      // u_512           [11][BB]
#define WS_CF   (22*BB)
#define WS_EF   (23*BB)
#define WS_CB   (24*BB)
#define WS_EB   (25*BB)
#define WS_NLL  (26*BB)
#define WS_FLOATS (27*BB)

__device__ __forceinline__ unsigned short f2bf(float f) {   // RTNE f32->bf16
    unsigned u = __float_as_uint(f);
    u += 0x7FFFu + ((u >> 16) & 1u);
    return (unsigned short)(u >> 16);
}
__device__ __forceinline__ unsigned pack2(float lo, float hi) {
    return (unsigned)f2bf(lo) | ((unsigned)f2bf(hi) << 16);
}

// MFMA with hazard nops (verified r12): s_nop 1 covers VALU->MFMA B-read;
// s_nop 7+3 cover MFMA->VALU D-read.
#define MFMA_STEP(D, A, B, C)                                              \
    asm volatile("s_nop 1\n\t"                                             \
                 "v_mfma_f32_16x16x16_bf16 %0, %1, %2, %3\n\t"             \
                 "s_nop 7\n\t"                                             \
                 "s_nop 3"                                                 \
                 : "=&v"(D) : "v"(A), "v"(B), "v"(C))
#define CVTPK(dst, lo, hi)                                                 \
    asm volatile("v_cvt_pk_bf16_f32 %0, %1, %2" : "=v"(dst) : "v"(lo), "v"(hi))

// One step (16 batch-steps): D = A x B; alpha = D*exp(e)*(pending scale);
// repack bf16. Rescale every 8 steps (exact power-of-2, per batch column).
#define MSTEP(JJ, E0v, E1v, E2v, E3v, TG)                                  \
    {                                                                      \
        float X0 = __expf(E0v), X1 = __expf(E1v);                          \
        float X2 = __expf(E2v), X3 = __expf(E3v);                          \
        if (((JJ) & 7) == 0) { cacc += eeP * LN2;                          \
            X0 *= scP; X1 *= scP; X2 *= scP; X3 *= scP; }                  \
        v4f D;                                                             \
        MFMA_STEP(D, Af, Bf, CZ);                                          \
        float t0 = D.x * X0, t1 = D.y * X1;                                \
        float t2 = D.z * X2, t3 = D.w * X3;                                \
        if (((JJ) & 7) == 7) {                                             \
            float mm = fmaxf(fmaxf(t0, t1), fmaxf(t2, t3));                \
            mm = fmaxf(mm, __shfl_xor(mm, 16, 64));                        \
            mm = fmaxf(mm, __shfl_xor(mm, 32, 64));                        \
            const int ee = (int)((__float_as_uint(mm) >> 23) & 0xFFu) - 127; \
            scP = __uint_as_float((unsigned)(127 - ee) << 23);             \
            eeP = (float)ee;                                               \
        }                                                                  \
        unsigned pb0, pb1;                                                 \
        CVTPK(pb0, t0, t1); CVTPK(pb1, t2, t3);                            \
        Bf.x = pb0; Bf.y = pb1;                                            \
        cur.x = t0; cur.y = t1; cur.z = t2; cur.w = t3;                    \
        if (((TG) >> 2) == g) {                                            \
            const int lo2 = (TG) & 3;                                      \
            em += (lo2 == 0) ? (E0v) : (lo2 == 1) ? (E1v)                  \
                : (lo2 == 2) ? (E2v) : (E3v);                              \
        }                                                                  \
    }

// ---------------------------------------------------------------------------
// MFMA scan (r12-verified algebra + register fix): 16 batches per wave.
// DIR=+1: fwd t=0..511 -> v=M^T a_511.  DIR=-1: bwd t=1023..512 -> u_512.
// ---------------------------------------------------------------------------
template<int DIR>
__device__ __forceinline__ void scan_mfma(const float* __restrict__ e,
                                          const int*   __restrict__ tags,
                                          const float* sT,
                                          float*       __restrict__ ws,
                                          int b0, int l)
{
    const int g = l >> 4;           // row group: B/D rows 4g..4g+3
    const int j = l & 15;           // batch column
    const int b = b0 + j;
    // Per-row e columns, ALL clamped to KTAGS-1 (r14 bug: g=3 rows 12..14 were
    // unclamped -> OOB read past the end of e -> device abort). Rows >= 11 are
    // the zero-pad rows of D, so their e value is multiplied by 0 — it only
    // needs to be in-bounds/finite, never correct.
    const int c0 = (4 * g + 0 < KTAGS) ? 4 * g + 0 : KTAGS - 1;
    const int c1 = (4 * g + 1 < KTAGS) ? 4 * g + 1 : KTAGS - 1;
    const int c2 = (4 * g + 2 < KTAGS) ? 4 * g + 2 : KTAGS - 1;
    const int c3 = (4 * g + 3 < KTAGS) ? 4 * g + 3 : KTAGS - 1;

    // A fragment: lane l reg r holds A[m=j][k=4g+r] (verified r12).
    // fwd: A = M^T (A[j][s]=exp(T[s][j])); bwd: A = M (A[j][s]=exp(T[j][s])).
    v2u Af;
    {
        float af[4];
#pragma unroll
        for (int r = 0; r < 4; ++r) {
            const int s = 4 * g + r;
            float v = 0.f;
            if (s < KTAGS && j < KTAGS)
                v = (DIR > 0) ? __expf(sT[s * SS + j]) : __expf(sT[j * SS + s]);
            af[r] = v;
        }
        Af.x = pack2(af[0], af[1]);
        Af.y = pack2(af[2], af[3]);
    }
    v4f CZ = {0.f, 0.f, 0.f, 0.f};

    // -------- init (fwd: t=0, bwd: t=1023) --------
    const size_t base = (size_t)b * TT;
    const int t0i = (DIR > 0) ? 0 : (TT - 1);
    const float* er = e + (base + t0i) * KTAGS;
    const float i0 = er[c0], i1 = er[c1], i2 = er[c2], i3 = er[c3];
    const int tg0 = tags[base + t0i];

    float em, cacc = 0.f, scP = 1.f, eeP = 0.f;
    v2u Bf;
    v4f cur = CZ;
    {
        float a0r[4];
        const float iv[4] = {i0, i1, i2, i3};
#pragma unroll
        for (int r = 0; r < 4; ++r) {
            const int s = 4 * g + r;
            a0r[r] = (s < KTAGS)
                       ? ((DIR > 0) ? __expf(sT[(SS - 2) * SS + s] + iv[r])   // T[START,s]+e
                                    : __expf(iv[r] + sT[s * SS + (SS - 1)]))  // e+T[s,STOP]
                       : 0.f;
        }
        Bf.x = pack2(a0r[0], a0r[1]);
        Bf.y = pack2(a0r[2], a0r[3]);
        em = ((tg0 >> 2) == g)
               ? (((tg0 & 3) == 0) ? i0 : ((tg0 & 3) == 1) ? i1
                  : ((tg0 & 3) == 2) ? i2 : i3)
               : 0.f;
    }

    // -------- pipelines: e/tags lead = UNR steps, per-row pointers --------
    const int tstart = (DIR > 0) ? 1 : (TT - 2);
    const float* p0 = e + (base + tstart) * KTAGS + c0;
    const float* p1 = e + (base + tstart) * KTAGS + c1;
    const float* p2 = e + (base + tstart) * KTAGS + c2;
    const float* p3 = e + (base + tstart) * KTAGS + c3;
    const int*   pt = tags + base + tstart;

    float eb0[UNR], eb1[UNR], eb2[UNR], eb3[UNR];
    int   tb_[UNR];
#pragma unroll
    for (int jj = 0; jj < UNR; ++jj) {
        eb0[jj] = p0[DIR * jj * KTAGS];
        eb1[jj] = p1[DIR * jj * KTAGS];
        eb2[jj] = p2[DIR * jj * KTAGS];
        eb3[jj] = p3[DIR * jj * KTAGS];
        tb_[jj] = pt[DIR * jj];
    }
    const float* q0 = p0 + DIR * UNR * KTAGS;
    const float* q1 = p1 + DIR * UNR * KTAGS;
    const float* q2 = p2 + DIR * UNR * KTAGS;
    const float* q3 = p3 + DIR * UNR * KTAGS;
    const int*   qt = pt + DIR * UNR;

    // main: updates 0..495
    for (int tb = 0; tb + 2 * UNR <= (HALF - 1); tb += UNR) {
#pragma unroll
        for (int jj = 0; jj < UNR; ++jj) {
            const float E0 = eb0[jj], E1 = eb1[jj], E2 = eb2[jj], E3 = eb3[jj];
            const int TG = tb_[jj];
            eb0[jj] = q0[DIR * jj * KTAGS];
            eb1[jj] = q1[DIR * jj * KTAGS];
            eb2[jj] = q2[DIR * jj * KTAGS];
            eb3[jj] = q3[DIR * jj * KTAGS];
            tb_[jj] = qt[DIR * jj];
            MSTEP(jj, E0, E1, E2, E3, TG)
        }
        q0 += DIR * UNR * KTAGS; q1 += DIR * UNR * KTAGS;
        q2 += DIR * UNR * KTAGS; q3 += DIR * UNR * KTAGS;
        qt += DIR * UNR;
    }
    // penultimate: updates 496..503; refill jj<7 (updates 504..510)
#pragma unroll
    for (int jj = 0; jj < UNR; ++jj) {
        const float E0 = eb0[jj], E1 = eb1[jj], E2 = eb2[jj], E3 = eb3[jj];
        const int TG = tb_[jj];
        if (jj < UNR - 1) {
            eb0[jj] = q0[DIR * jj * KTAGS];
            eb1[jj] = q1[DIR * jj * KTAGS];
            eb2[jj] = q2[DIR * jj * KTAGS];
            eb3[jj] = q3[DIR * jj * KTAGS];
            tb_[jj] = qt[DIR * jj];
        }
        MSTEP(jj, E0, E1, E2, E3, TG)
    }
    // tail: updates 504..510
#pragma unroll
    for (int jj = 0; jj < UNR - 1; ++jj) {
        MSTEP(jj, eb0[jj], eb1[jj], eb2[jj], eb3[jj], tb_[jj])
    }

    // -------- epilogue --------
    em += __shfl_xor(em, 16, 64);
    em += __shfl_xor(em, 32, 64);
    const int s0 = 4 * g;

    if (DIR > 0) {
        v4f Dv;
        MFMA_STEP(Dv, Af, Bf, CZ);      // v = M^T a_511
        if (s0 + 0 < KTAGS) ws[WS_VA + (s0 + 0) * BB + b] = Dv.x;
        if (s0 + 1 < KTAGS) ws[WS_VA + (s0 + 1) * BB + b] = Dv.y;
        if (s0 + 2 < KTAGS) ws[WS_VA + (s0 + 2) * BB + b] = Dv.z;
        if (s0 + 3 < KTAGS) ws[WS_VA + (s0 + 3) * BB + b] = Dv.w;
        if (l < 16) { ws[WS_CF + b] = cacc; ws[WS_EF + b] = em; }
    } else {
        if (s0 + 0 < KTAGS) ws[WS_UB + (s0 + 0) * BB + b] = cur.x;
        if (s0 + 1 < KTAGS) ws[WS_UB + (s0 + 1) * BB + b] = cur.y;
        if (s0 + 2 < KTAGS) ws[WS_UB + (s0 + 2) * BB + b] = cur.z;
        if (s0 + 3 < KTAGS) ws[WS_UB + (s0 + 3) * BB + b] = cur.w;
        if (l < 16) { ws[WS_CB + b] = cacc; ws[WS_EB + b] = em; }
    }
}

// __launch_bounds__(64, 1): only 512 waves exist (0.5/SIMD), so cap VGPRs at
// the 1-wave/EU budget instead of the default 8-wave budget (64 VGPRs).
// r12's 60-VGPR allocation spilled ~70 live values to scratch.
__global__ __launch_bounds__(64, 1)
void crf_mfma_kernel(const float* __restrict__ e,
                     const float* __restrict__ Tmat,
                     const int*   __restrict__ tags,
                     float*       __restrict__ ws)
{
    __shared__ float sT[SS * SS];
    const int tid = threadIdx.x;
    for (int i = tid; i < SS * SS; i += 64) sT[i] = Tmat[i];
    __syncthreads();
    const int p = (int)blockIdx.x;
    if (p < BB / 16) scan_mfma<+1>(e, tags, sT, ws, p * 16, tid);
    else             scan_mfma<-1>(e, tags, sT, ws, (p - BB / 16) * 16, tid);
}

// combine: nll[b] = cacc_f + cacc_b + log(v.u) - em_f - em_b
__global__ __launch_bounds__(256)
void combine_kernel(float* __restrict__ ws)
{
    const int b = blockIdx.x * 256 + threadIdx.x;
    double dot = 0.0;
#pragma unroll
    for (int s = 0; s < KTAGS; ++s)
        dot += (double)ws[WS_VA + s * BB + b] * (double)ws[WS_UB + s * BB + b];
    const double logZ = (double)ws[WS_CF + b] + (double)ws[WS_CB + b] + log(dot);
    ws[WS_NLL + b] = (float)logZ - ws[WS_EF + b] - ws[WS_EB + b];
}

// gold transition/START/STOP sum, subtracted from nll[b] (verified r9-r13)
__global__ __launch_bounds__(64)
void gold_kernel(const float* __restrict__ Tmat,
                 const int*   __restrict__ tags,
                 float*       __restrict__ nll)
{
    __shared__ float sT[SS * SS];
    __shared__ int   stg[TT];
    const int tid = threadIdx.x;
    const int b   = blockIdx.x;

    for (int i = tid; i < SS * SS; i += 64) sT[i] = Tmat[i];
    const int4* tg4 = (const int4*)(tags + (size_t)b * TT);
    int4* s4 = (int4*)stg;
#pragma unroll
    for (int k = 0; k < TT / 4 / 64; ++k) s4[tid + 64 * k] = tg4[tid + 64 * k];
    __syncthreads();

    float s = 0.f;
    const int t0 = tid * 16;
#pragma unroll
    for (int k = 1; k <= 16; ++k) {
        const int t = t0 + k;
        if (t < TT) s += sT[stg[t - 1] * SS + stg[t]];
    }
    if (tid == 0) {
        s += sT[(SS - 2) * SS + stg[0]];
        s += sT[stg[TT - 1] * SS + (SS - 1)];
    }
#pragma unroll
    for (int d = 32; d >= 1; d >>= 1) s += __shfl_xor(s, d, 64);
    if (tid == 0) nll[b] -= s;
}

// Deterministic mean over B values (double accumulation).
__global__ __launch_bounds__(256)
void reduce_mean_kernel(const float* __restrict__ v, float* __restrict__ out, int n)
{
    __shared__ double sbuf[256];
    double s = 0.0;
    for (int i = threadIdx.x; i < n; i += 256) s += (double)v[i];
    sbuf[threadIdx.x] = s;
    __syncthreads();
    for (int k = 128; k > 0; k >>= 1) {
        if ((int)threadIdx.x < k) sbuf[threadIdx.x] += sbuf[threadIdx.x + k];
        __syncthreads();
    }
    if (threadIdx.x == 0) out[0] = (float)(sbuf[0] / (double)n);
}

// ---------------------------------------------------------------------------
// Fallback (r9-verified DPP full scan), used only if ws is too small.
// ---------------------------------------------------------------------------
#define ROTSUM(A0,A1,A2,A3,SRC)                                                \
        asm volatile(                                                          \
          "s_nop 1\n\t"                                                        \
          "v_mul_f32 %0, %4, %5\n\t"                                           \
          "v_mul_f32_dpp %1, %4, %6  row_ror:1  row_mask:0xf bank_mask:0xf\n\t"\
          "v_mul_f32_dpp %2, %4, %7  row_ror:2  row_mask:0xf bank_mask:0xf\n\t"\
          "v_mul_f32_dpp %3, %4, %8  row_ror:3  row_mask:0xf bank_mask:0xf\n\t"\
          "v_fmac_f32_dpp %0, %4, %9  row_ror:4  row_mask:0xf bank_mask:0xf\n\t"\
          "v_fmac_f32_dpp %1, %4, %10 row_ror:5  row_mask:0xf bank_mask:0xf\n\t"\
          "v_fmac_f32_dpp %2, %4, %11 row_ror:6  row_mask:0xf bank_mask:0xf\n\t"\
          "v_fmac_f32_dpp %3, %4, %12 row_ror:7  row_mask:0xf bank_mask:0xf\n\t"\
          "v_fmac_f32_dpp %0, %4, %13 row_ror:8  row_mask:0xf bank_mask:0xf\n\t"\
          "v_fmac_f32_dpp %1, %4, %14 row_ror:9  row_mask:0xf bank_mask:0xf\n\t"\
          "v_fmac_f32_dpp %2, %4, %15 row_ror:10 row_mask:0xf bank_mask:0xf\n\t"\
          "v_fmac_f32_dpp %3, %4, %16 row_ror:11 row_mask:0xf bank_mask:0xf\n\t"\
          "v_fmac_f32_dpp %0, %4, %17 row_ror:12 row_mask:0xf bank_mask:0xf\n\t"\
          "v_fmac_f32_dpp %1, %4, %18 row_ror:13 row_mask:0xf bank_mask:0xf\n\t"\
          "v_fmac_f32_dpp %2, %4, %19 row_ror:14 row_mask:0xf bank_mask:0xf\n\t"\
          "v_fmac_f32_dpp %3, %4, %20 row_ror:15 row_mask:0xf bank_mask:0xf\n\t"\
          : "=&v"(A0), "=&v"(A1), "=&v"(A2), "=&v"(A3)                         \
          : "v"(SRC), "v"(W[0]), "v"(W[1]), "v"(W[2]),  "v"(W[3]),             \
            "v"(W[4]), "v"(W[5]), "v"(W[6]),  "v"(W[7]), "v"(W[8]),            \
            "v"(W[9]), "v"(W[10]), "v"(W[11]), "v"(W[12]), "v"(W[13]),         \
            "v"(W[14]), "v"(W[15]))

#define MAXRED(MM, SRC)                                                        \
        asm volatile(                                                          \
          "s_nop 1\n\t"                                                        \
          "v_max_f32_dpp %0, %1, %1 row_ror:8 row_mask:0xf bank_mask:0xf\n\t"  \
          "s_nop 1\n\t"                                                        \
          "v_max_f32_dpp %0, %0, %0 row_ror:4 row_mask:0xf bank_mask:0xf\n\t"  \
          "s_nop 1\n\t"                                                        \
          "v_max_f32_dpp %0, %0, %0 quad_perm:[1,0,3,2] row_mask:0xf bank_mask:0xf\n\t"\
          "s_nop 1\n\t"                                                        \
          "v_max_f32_dpp %0, %0, %0 quad_perm:[2,3,0,1] row_mask:0xf bank_mask:0xf\n\t"\
          : "=&v"(MM) : "v"(SRC))

#define DSTEP(J, E_T, TG)                                                      \
    {                                                                          \
        const float X_T = __expf(E_T);                                         \
        float ac0, ac1, ac2, ac3;                                              \
        ROTSUM(ac0, ac1, ac2, ac3, aP);                                        \
        float xsc = X_T;                                                       \
        if (((J) & 7) == 0) { cacc += eeP * LN2; xsc *= scP; }                 \
        aP = ((ac0 + ac1) + (ac2 + ac3)) * xsc;                                \
        if (((J) & 7) == 7) {                                                  \
            float mm;                                                          \
            MAXRED(mm, aP);                                                    \
            const int ee = (int)((__float_as_uint(mm) >> 23) & 0xFFu) - 127;   \
            scP = __uint_as_float((unsigned)(127 - ee) << 23);                 \
            eeP = (float)ee;                                                   \
        }                                                                      \
        em_acc += (to == (TG)) ? (E_T) : 0.f;                                  \
    }

__global__ __launch_bounds__(64)
void crf_scan_full_kernel(const float* __restrict__ e,
                          const float* __restrict__ Tmat,
                          const int*   __restrict__ tags,
                          float*       __restrict__ out_per_b)
{
    __shared__ float sT[SS * SS];
    const int tid = threadIdx.x;
    for (int i = tid; i < SS * SS; i += 64) sT[i] = Tmat[i];

    const int g   = tid >> 4;
    const int to  = tid & 15;
    const int toT = (to < SS) ? to : (SS - 1);
    const int toE = (to < KTAGS) ? to : (KTAGS - 1);
    const int b   = blockIdx.x * GPW + g;
    __syncthreads();

    float W[16];
#pragma unroll
    for (int r = 0; r < 16; ++r) {
        const int f = (to - r) & 15;
        W[r] = (f < KTAGS && to <= SS - 1 && to != KTAGS)
                 ? __expf(sT[f * SS + toT]) : 0.f;
        if (to >= SS) W[r] = 0.f;
    }
    const float eTstop = __expf(sT[toT * SS + (SS - 1)]);

    const float* pe  = e    + (size_t)b * TT * KTAGS + toE;
    const int*   tgp = tags + (size_t)b * TT;

    const float e0  = pe[0];
    const int   tg0 = tgp[0];
    float aP = (to < SS) ? __expf(sT[(SS - 2) * SS + toT] + e0) : 0.f;
    float cacc = 0.f;
    float em_acc = (to == tg0) ? e0 : 0.f;

    float ebuf[16]; int tbuf[16];
#pragma unroll
    for (int j = 0; j < 16; ++j) {
        ebuf[j] = pe[(size_t)(1 + j) * KTAGS];
        tbuf[j] = tgp[1 + j];
    }
    float scP = 1.f, eeP = 0.f;

    const float* qe = pe  + (size_t)17 * KTAGS;
    const int*   qt = tgp + 17;
    for (int tb = 1; tb + 32 <= TT; tb += 16) {
#pragma unroll
        for (int j = 0; j < 16; ++j) {
            const float E_T = ebuf[j];
            const int   TG  = tbuf[j];
            ebuf[j] = qe[j * KTAGS];
            tbuf[j] = qt[j];
            DSTEP(j, E_T, TG)
        }
        qe += (size_t)16 * KTAGS; qt += 16;
    }
#pragma unroll
    for (int j = 0; j < 16; ++j) {
        const float E_T = ebuf[j];
        const int   TG  = tbuf[j];
        if (j < 15) { ebuf[j] = qe[j * KTAGS]; tbuf[j] = qt[j]; }
        DSTEP(j, E_T, TG)
    }
#pragma unroll
    for (int j = 0; j < 15; ++j) {
        DSTEP(j, ebuf[j], tbuf[j])
    }

    float z  = (to < KTAGS) ? aP * eTstop : 0.f;
    float em = em_acc;
#pragma unroll
    for (int s = 8; s >= 1; s >>= 1) {
        z  += __shfl_xor(z,  s, 16);
        em += __shfl_xor(em, s, 16);
    }
    if (to == 0) {
        const float logZ = cacc + __logf(z);
        out_per_b[b] = logZ - em;
    }
}

extern "C" void kernel_launch(void* const* d_in, const int* in_sizes, int n_in,
                              void* d_out, int out_size, void* d_ws, size_t ws_size,
                              hipStream_t stream)
{
    const float* e    = (const float*)d_in[0];
    const float* Tmat = (const float*)d_in[1];
    const int*   tags = (const int*)d_in[2];
    // d_in[3] = mask: all-true in this problem; kernel implements the all-true path.

    float* ws  = (float*)d_ws;
    float* out = (float*)d_out;

    if (ws_size >= (size_t)WS_FLOATS * sizeof(float)) {
        crf_mfma_kernel<<<2 * (BB / 16), 64, 0, stream>>>(e, Tmat, tags, ws);
        combine_kernel<<<BB / 256, 256, 0, stream>>>(ws);
        gold_kernel<<<BB, 64, 0, stream>>>(Tmat, tags, ws + WS_NLL);
        reduce_mean_kernel<<<1, 256, 0, stream>>>(ws + WS_NLL, out, BB);
    } else {
        crf_scan_full_kernel<<<BB / GPW, 64, 0, stream>>>(e, Tmat, tags, ws);
        gold_kernel<<<BB, 64, 0, stream>>>(Tmat, tags, ws);
        reduce_mean_kernel<<<1, 256, 0, stream>>>(ws, out, BB);
    }
}

// Round 16
// 78.963 us; speedup vs baseline: 2.1322x; 2.1322x over previous
//
#include <hip/hip_runtime.h>

#define KTAGS 11
#define SS    13
#define TT    1024
#define BB    4096
#define GPW   4      // chains per 64-thread block (16 lanes per chain)
#define UNR   16     // steps per unrolled block == e/tags pipeline depth (full kernel)
#define PUNR  8      // pair-half unroll (511 = 62*8 + 8 + 7)
#define HALF  512
#define LN2   0.6931471805599453f

// ws layout (floats)
#define WS_VA   0            // v = M^T a_511   [11][BB]
#define WS_UB   (11*BB)      // u_512           [11][BB]
#define WS_CF   (22*BB)
#define WS_EF   (23*BB)
#define WS_CB   (24*BB)
#define WS_EB   (25*BB)
#define WS_NLL  (26*BB)
#define WS_FLOATS (27*BB)

// Fused rotate-multiply-accumulate: 4 DPP muls + 12 DPP fmacs (verified r5-r13).
#define ROTSUM(A0,A1,A2,A3,SRC)                                                \
        asm volatile(                                                          \
          "s_nop 1\n\t"                                                        \
          "v_mul_f32 %0, %4, %5\n\t"                                           \
          "v_mul_f32_dpp %1, %4, %6  row_ror:1  row_mask:0xf bank_mask:0xf\n\t"\
          "v_mul_f32_dpp %2, %4, %7  row_ror:2  row_mask:0xf bank_mask:0xf\n\t"\
          "v_mul_f32_dpp %3, %4, %8  row_ror:3  row_mask:0xf bank_mask:0xf\n\t"\
          "v_fmac_f32_dpp %0, %4, %9  row_ror:4  row_mask:0xf bank_mask:0xf\n\t"\
          "v_fmac_f32_dpp %1, %4, %10 row_ror:5  row_mask:0xf bank_mask:0xf\n\t"\
          "v_fmac_f32_dpp %2, %4, %11 row_ror:6  row_mask:0xf bank_mask:0xf\n\t"\
          "v_fmac_f32_dpp %3, %4, %12 row_ror:7  row_mask:0xf bank_mask:0xf\n\t"\
          "v_fmac_f32_dpp %0, %4, %13 row_ror:8  row_mask:0xf bank_mask:0xf\n\t"\
          "v_fmac_f32_dpp %1, %4, %14 row_ror:9  row_mask:0xf bank_mask:0xf\n\t"\
          "v_fmac_f32_dpp %2, %4, %15 row_ror:10 row_mask:0xf bank_mask:0xf\n\t"\
          "v_fmac_f32_dpp %3, %4, %16 row_ror:11 row_mask:0xf bank_mask:0xf\n\t"\
          "v_fmac_f32_dpp %0, %4, %17 row_ror:12 row_mask:0xf bank_mask:0xf\n\t"\
          "v_fmac_f32_dpp %1, %4, %18 row_ror:13 row_mask:0xf bank_mask:0xf\n\t"\
          "v_fmac_f32_dpp %2, %4, %19 row_ror:14 row_mask:0xf bank_mask:0xf\n\t"\
          "v_fmac_f32_dpp %3, %4, %20 row_ror:15 row_mask:0xf bank_mask:0xf\n\t"\
          : "=&v"(A0), "=&v"(A1), "=&v"(A2), "=&v"(A3)                         \
          : "v"(SRC), "v"(W[0]), "v"(W[1]), "v"(W[2]),  "v"(W[3]),             \
            "v"(W[4]), "v"(W[5]), "v"(W[6]),  "v"(W[7]), "v"(W[8]),            \
            "v"(W[9]), "v"(W[10]), "v"(W[11]), "v"(W[12]), "v"(W[13]),         \
            "v"(W[14]), "v"(W[15]))

#define MAXRED(MM, SRC)                                                        \
        asm volatile(                                                          \
          "s_nop 1\n\t"                                                        \
          "v_max_f32_dpp %0, %1, %1 row_ror:8 row_mask:0xf bank_mask:0xf\n\t"  \
          "s_nop 1\n\t"                                                        \
          "v_max_f32_dpp %0, %0, %0 row_ror:4 row_mask:0xf bank_mask:0xf\n\t"  \
          "s_nop 1\n\t"                                                        \
          "v_max_f32_dpp %0, %0, %0 quad_perm:[1,0,3,2] row_mask:0xf bank_mask:0xf\n\t"\
          "s_nop 1\n\t"                                                        \
          "v_max_f32_dpp %0, %0, %0 quad_perm:[2,3,0,1] row_mask:0xf bank_mask:0xf\n\t"\
          : "=&v"(MM) : "v"(SRC))

// Rescale every 8 steps: apply pending at (J&7)==0, sample post-update at (J&7)==7.
#define STEP(J, E_T, TG)                                                       \
    {                                                                          \
        const float X_T = __expf(E_T);                                         \
        float ac0, ac1, ac2, ac3;                                              \
        ROTSUM(ac0, ac1, ac2, ac3, aP);                                        \
        float xsc = X_T;                                                       \
        if (((J) & 7) == 0) { cacc += eeP * LN2; xsc *= scP; }                 \
        aP = ((ac0 + ac1) + (ac2 + ac3)) * xsc;                                \
        if (((J) & 7) == 7) {                                                  \
            float mm;                                                          \
            MAXRED(mm, aP);                                                    \
            const int ee = (int)((__float_as_uint(mm) >> 23) & 0xFFu) - 127;   \
            scP = __uint_as_float((unsigned)(127 - ee) << 23);                 \
            eeP = (float)ee;                                                   \
        }                                                                      \
        em_acc += (to == (TG)) ? (E_T) : 0.f;                                  \
    }

// ---------------------------------------------------------------------------
// Half-scan (hot loop byte-identical to r10/r13; NEW: fused gold-transition
// epilogue). DIR=+1: fwd t=0..511 -> v=M^T a_511; also sums T[START,tag0] +
// trans(t=1..511) into em. DIR=-1: bwd t=1023..512 -> u_512; also sums
// trans(t=512..1023) + T[tag1023,STOP] into em.
// ---------------------------------------------------------------------------
template<int DIR>
__device__ __forceinline__ void scan_dir(const float* __restrict__ e,
                                         const int*   __restrict__ tags,
                                         const float* sT,
                                         float*       __restrict__ ws,
                                         int b, int to)
{
    const int toT = (to < SS) ? to : (SS - 1);
    const int toE = (to < KTAGS) ? to : (KTAGS - 1);

    float W[16];
#pragma unroll
    for (int r = 0; r < 16; ++r) {
        const int f = (to - r) & 15;
        if (DIR > 0) {
            W[r] = (f < KTAGS && to <= SS - 1 && to != KTAGS)
                     ? __expf(sT[f * SS + toT]) : 0.f;
            if (to >= SS) W[r] = 0.f;
        } else {
            W[r] = (to < KTAGS && f < KTAGS) ? __expf(sT[to * SS + f]) : 0.f;
        }
    }

    const float* ebase = e    + (size_t)b * TT * KTAGS + toE;
    const int*   tbase = tags + (size_t)b * TT;

    float aP, em_acc, cacc = 0.f;
    if (DIR > 0) {
        const float E0 = ebase[0];
        const int   tg0 = tbase[0];
        aP = (to < SS) ? __expf(sT[(SS - 2) * SS + toT] + E0) : 0.f;
        em_acc = (to == tg0) ? E0 : 0.f;
    } else {
        const float E0 = ebase[(size_t)(TT - 1) * KTAGS];
        const int   tg0 = tbase[TT - 1];
        aP = (to < KTAGS) ? __expf(E0 + sT[toT * SS + (SS - 1)]) : 0.f;
        em_acc = (to == tg0) ? E0 : 0.f;
    }

    // update j (0..510) consumes e/tag at t = DIR>0 ? 1+j : 1022-j
    const ptrdiff_t estep = (ptrdiff_t)DIR * KTAGS;
    const float* peU = ebase + ((DIR > 0) ? (ptrdiff_t)KTAGS : (ptrdiff_t)(TT - 2) * KTAGS);
    const int*   tgU = tbase + ((DIR > 0) ? 1 : (TT - 2));

    float ebuf[PUNR]; int tbuf[PUNR];
#pragma unroll
    for (int j = 0; j < PUNR; ++j) {
        ebuf[j] = peU[estep * j];
        tbuf[j] = tgU[DIR * j];
    }

    float scP = 1.f, eeP = 0.f;
    const float* qe = peU + estep * PUNR;
    const int*   qt = tgU + DIR * PUNR;

    // main: updates 0..495
    for (int tb = 0; tb + 2 * PUNR <= (HALF - 1); tb += PUNR) {
#pragma unroll
        for (int j = 0; j < PUNR; ++j) {
            const float E_T = ebuf[j];
            const int   TG  = tbuf[j];
            ebuf[j] = qe[estep * j];
            tbuf[j] = qt[DIR * j];
            STEP(j, E_T, TG)
        }
        qe += estep * PUNR; qt += DIR * PUNR;
    }
    // penultimate: updates 496..503; refill j<7 (504..510)
#pragma unroll
    for (int j = 0; j < PUNR; ++j) {
        const float E_T = ebuf[j];
        const int   TG  = tbuf[j];
        if (j < PUNR - 1) { ebuf[j] = qe[estep * j]; tbuf[j] = qt[DIR * j]; }
        STEP(j, E_T, TG)
    }
    // tail: updates 504..510
#pragma unroll
    for (int j = 0; j < PUNR - 1; ++j) {
        STEP(j, ebuf[j], tbuf[j])
    }

    // ---- NEW: fused gold transition sum for this half (off the hot path) ----
    // fwd covers transitions t = 1..511 (+ T[START,tag0]); bwd covers
    // t = 512..1023 (+ T[tag1023,STOP]). Together: all 1023 transitions.
    {
        float tr = 0.f;
        const int t0   = (DIR > 0) ? 1 : HALF;
        const int tlim = (DIR > 0) ? (HALF - 1) : (TT - 1);
#pragma unroll 4
        for (int k = 0; k < 32; ++k) {
            const int t = t0 + to + 16 * k;
            if (t <= tlim) {
                const int ta = tbase[t - 1];
                const int tc = tbase[t];
                tr += sT[ta * SS + tc];
            }
        }
        if (to == 0) {
            if (DIR > 0) tr += sT[(SS - 2) * SS + tbase[0]];        // T[START, tag0]
            else         tr += sT[tbase[TT - 1] * SS + (SS - 1)];   // T[tag1023, STOP]
        }
        em_acc += tr;   // rides the existing em reduction; combine subtracts em_f+em_b
    }

    // epilogue: group-sum em; write vectors + scalars
    float em = em_acc;
#pragma unroll
    for (int s = 8; s >= 1; s >>= 1) em += __shfl_xor(em, s, 16);

    if (DIR > 0) {
        float ac0, ac1, ac2, ac3;
        ROTSUM(ac0, ac1, ac2, ac3, aP);       // v = M^T a_511
        const float v = (ac0 + ac1) + (ac2 + ac3);
        if (to < KTAGS) ws[WS_VA + to * BB + b] = v;
        if (to == 0) { ws[WS_CF + b] = cacc; ws[WS_EF + b] = em; }
    } else {
        if (to < KTAGS) ws[WS_UB + to * BB + b] = aP;
        if (to == 0) { ws[WS_CB + b] = cacc; ws[WS_EB + b] = em; }
    }
}

__global__ __launch_bounds__(64, 2)
void crf_scan2_kernel(const float* __restrict__ e,
                      const float* __restrict__ Tmat,
                      const int*   __restrict__ tags,
                      float*       __restrict__ ws)
{
    __shared__ float sT[SS * SS];
    const int tid = threadIdx.x;
    for (int i = tid; i < SS * SS; i += 64) sT[i] = Tmat[i];
    __syncthreads();

    const int g  = tid >> 4;
    const int to = tid & 15;
    const int b  = ((int)blockIdx.x & (BB / GPW - 1)) * GPW + g;

    if ((int)blockIdx.x < BB / GPW) scan_dir<+1>(e, tags, sT, ws, b, to);
    else                            scan_dir<-1>(e, tags, sT, ws, b, to);
}

// combine: nll[b] = cacc_f + cacc_b + log(v.u) - em_f - em_b
// (em_* now already include the gold transition/START/STOP terms)
__global__ __launch_bounds__(256)
void combine_kernel(float* __restrict__ ws)
{
    const int b = blockIdx.x * 256 + threadIdx.x;
    double dot = 0.0;
#pragma unroll
    for (int s = 0; s < KTAGS; ++s)
        dot += (double)ws[WS_VA + s * BB + b] * (double)ws[WS_UB + s * BB + b];
    const float logZ = (float)((double)ws[WS_CF + b] + (double)ws[WS_CB + b] + log(dot));
    ws[WS_NLL + b] = logZ - ws[WS_EF + b] - ws[WS_EB + b];
}

// Deterministic mean over B values (double accumulation).
__global__ __launch_bounds__(256)
void reduce_mean_kernel(const float* __restrict__ v, float* __restrict__ out, int n)
{
    __shared__ double sbuf[256];
    double s = 0.0;
    for (int i = threadIdx.x; i < n; i += 256) s += (double)v[i];
    sbuf[threadIdx.x] = s;
    __syncthreads();
    for (int k = 128; k > 0; k >>= 1) {
        if ((int)threadIdx.x < k) sbuf[threadIdx.x] += sbuf[threadIdx.x + k];
        __syncthreads();
    }
    if (threadIdx.x == 0) out[0] = (float)(sbuf[0] / (double)n);
}

// ---------------------------------------------------------------------------
// Fallback path (r9-verified): full forward scan + separate gold kernel.
// Used only if ws is too small for the split layout.
// ---------------------------------------------------------------------------
__global__ __launch_bounds__(64)
void gold_kernel(const float* __restrict__ Tmat,
                 const int*   __restrict__ tags,
                 float*       __restrict__ nll)
{
    __shared__ float sT[SS * SS];
    __shared__ int   stg[TT];
    const int tid = threadIdx.x;
    const int b   = blockIdx.x;

    for (int i = tid; i < SS * SS; i += 64) sT[i] = Tmat[i];
    const int4* tg4 = (const int4*)(tags + (size_t)b * TT);
    int4* s4 = (int4*)stg;
#pragma unroll
    for (int k = 0; k < TT / 4 / 64; ++k) s4[tid + 64 * k] = tg4[tid + 64 * k];
    __syncthreads();

    float s = 0.f;
    const int t0 = tid * 16;
#pragma unroll
    for (int k = 1; k <= 16; ++k) {
        const int t = t0 + k;
        if (t < TT) s += sT[stg[t - 1] * SS + stg[t]];
    }
    if (tid == 0) {
        s += sT[(SS - 2) * SS + stg[0]];
        s += sT[stg[TT - 1] * SS + (SS - 1)];
    }
#pragma unroll
    for (int d = 32; d >= 1; d >>= 1) s += __shfl_xor(s, d, 64);
    if (tid == 0) nll[b] -= s;
}

__global__ __launch_bounds__(64)
void crf_scan_full_kernel(const float* __restrict__ e,
                          const float* __restrict__ Tmat,
                          const int*   __restrict__ tags,
                          float*       __restrict__ out_per_b)
{
    __shared__ float sT[SS * SS];
    const int tid = threadIdx.x;
    for (int i = tid; i < SS * SS; i += 64) sT[i] = Tmat[i];

    const int g   = tid >> 4;
    const int to  = tid & 15;
    const int toT = (to < SS) ? to : (SS - 1);
    const int toE = (to < KTAGS) ? to : (KTAGS - 1);
    const int b   = blockIdx.x * GPW + g;
    __syncthreads();

    float W[16];
#pragma unroll
    for (int r = 0; r < 16; ++r) {
        const int f = (to - r) & 15;
        W[r] = (f < KTAGS && to <= SS - 1 && to != KTAGS)
                 ? __expf(sT[f * SS + toT]) : 0.f;
        if (to >= SS) W[r] = 0.f;
    }
    const float eTstop = __expf(sT[toT * SS + (SS - 1)]);

    const float* pe  = e    + (size_t)b * TT * KTAGS + toE;
    const int*   tgp = tags + (size_t)b * TT;

    const float e0  = pe[0];
    const int   tg0 = tgp[0];
    float aP = (to < SS) ? __expf(sT[(SS - 2) * SS + toT] + e0) : 0.f;
    float cacc = 0.f;
    float em_acc = (to == tg0) ? e0 : 0.f;

    float ebuf[UNR]; int tbuf[UNR];
#pragma unroll
    for (int j = 0; j < UNR; ++j) {
        ebuf[j] = pe[(size_t)(1 + j) * KTAGS];
        tbuf[j] = tgp[1 + j];
    }
    float scP = 1.f, eeP = 0.f;

    const float* qe = pe  + (size_t)(1 + UNR) * KTAGS;
    const int*   qt = tgp + 1 + UNR;
    for (int tb = 1; tb + 2 * UNR <= TT; tb += UNR) {
#pragma unroll
        for (int j = 0; j < UNR; ++j) {
            const float E_T = ebuf[j];
            const int   TG  = tbuf[j];
            ebuf[j] = qe[j * KTAGS];
            tbuf[j] = qt[j];
            STEP(j, E_T, TG)
        }
        qe += (size_t)UNR * KTAGS; qt += UNR;
    }
#pragma unroll
    for (int j = 0; j < UNR; ++j) {
        const float E_T = ebuf[j];
        const int   TG  = tbuf[j];
        if (j < UNR - 1) { ebuf[j] = qe[j * KTAGS]; tbuf[j] = qt[j]; }
        STEP(j, E_T, TG)
    }
#pragma unroll
    for (int j = 0; j < UNR - 1; ++j) {
        STEP(j, ebuf[j], tbuf[j])
    }

    float z  = (to < KTAGS) ? aP * eTstop : 0.f;
    float em = em_acc;
#pragma unroll
    for (int s = 8; s >= 1; s >>= 1) {
        z  += __shfl_xor(z,  s, 16);
        em += __shfl_xor(em, s, 16);
    }
    if (to == 0) {
        const float logZ = cacc + __logf(z);
        out_per_b[b] = logZ - em;
    }
}

extern "C" void kernel_launch(void* const* d_in, const int* in_sizes, int n_in,
                              void* d_out, int out_size, void* d_ws, size_t ws_size,
                              hipStream_t stream)
{
    const float* e    = (const float*)d_in[0];
    const float* Tmat = (const float*)d_in[1];
    const int*   tags = (const int*)d_in[2];
    // d_in[3] = mask: all-true in this problem; kernel implements the all-true path.

    float* ws  = (float*)d_ws;
    float* out = (float*)d_out;

    if (ws_size >= (size_t)WS_FLOATS * sizeof(float)) {
        crf_scan2_kernel<<<2 * BB / GPW, 64, 0, stream>>>(e, Tmat, tags, ws);
        combine_kernel<<<BB / 256, 256, 0, stream>>>(ws);
        reduce_mean_kernel<<<1, 256, 0, stream>>>(ws + WS_NLL, out, BB);
    } else {
        crf_scan_full_kernel<<<BB / GPW, 64, 0, stream>>>(e, Tmat, tags, ws);
        gold_kernel<<<BB, 64, 0, stream>>>(Tmat, tags, ws);
        reduce_mean_kernel<<<1, 256, 0, stream>>>(ws, out, BB);
    }
}